// Round 10
// baseline (16693.042 us; speedup 1.0000x reference)
//
#include <hip/hip_runtime.h>

// ---------------------------------------------------------------------------
// 2-layer GRU, T=512, B=64, I=H=512, fp32 in/out. Persistent cooperative
// kernel, 64 WGs x 512 thr (8 waves), layers wavefront-pipelined.
// Round 10: MFMA split-bf16, weights register-stationary.
//  - WG owns 16 hidden cols x 3 gates (48 gate-rows), M=64(batch), K=1024.
//  - 6 compute waves = (gate, K-half). Each wave's B-fragments (16 rows x
//    512 K as bf16 hi+lo) live in 128 VGPRs for the whole kernel: ZERO
//    per-step weight traffic (the r5-r9 bottleneck).
//  - 3-term split product: ahi*Whi + ahi*Wlo + alo*Whi (err ~2^-17).
//  - A slabs pre-split bf16 hi/lo: x -> written into out[] slabs in the
//    prologue (slab t consumed at step t, overwritten by L2 at t+1);
//    h1 -> ring1, h2 -> ring2 (fresh-address T-deep rings in ws).
//  - exact fp32 h state kept in LDS per WG; epilogue = r/z/n gates.
//  - 64-flag packed barrier, sc0 sc1 write-through stores as in r5.
// ---------------------------------------------------------------------------

typedef float f32x4 __attribute__((ext_vector_type(4)));
typedef short s16x8 __attribute__((ext_vector_type(8)));
typedef unsigned u32x2 __attribute__((ext_vector_type(2)));
typedef unsigned u32x4 __attribute__((ext_vector_type(4)));

#define GB_T 512
#define NWG 64
#define NTHR 512

// float-word offsets inside ws
#define OFF_FLAGS 0
#define OFF_RING1 1024                       // 513 slabs x 32768 floats
#define OFF_RING2 (OFF_RING1 + 513 * 32768)  // 513 slabs x 32768 floats
// ws bytes = (1024 + 2*513*32768)*4 ~= 134.5 MB

__device__ __forceinline__ void st_coh_u32(unsigned* p, unsigned v) {
  asm volatile("global_store_dword %0, %1, off sc0 sc1" ::"v"(p), "v"(v)
               : "memory");
}
__device__ __forceinline__ void st_coh_u32x2(unsigned* p, u32x2 v) {
  asm volatile("global_store_dwordx2 %0, %1, off sc0 sc1" ::"v"(p), "v"(v)
               : "memory");
}
#define LDC4U(dst, addr)                                  \
  asm volatile("global_load_dwordx4 %0, %1, off sc0 sc1" \
               : "=v"(dst)                                \
               : "v"(addr))

__device__ __forceinline__ unsigned fbits(float f) {
  union { float f; unsigned u; } c; c.f = f; return c.u;
}
__device__ __forceinline__ float bcast_f(unsigned u) {
  union { unsigned u; float f; } c; c.u = u; return c.f;
}

// split a 32768-float slab into bf16 hi (32768 ushort) + lo (32768 ushort)
__device__ __forceinline__ void split_slab(const float* __restrict__ src,
                                           unsigned short* __restrict__ dst,
                                           int tid) {
  const f32x4* s4 = (const f32x4*)src;
#pragma unroll 4
  for (int u = 0; u < 16; ++u) {
    f32x4 v = s4[tid * 16 + u];
    unsigned b0 = fbits(v.x), b1 = fbits(v.y), b2 = fbits(v.z), b3 = fbits(v.w);
    unsigned hi0 = (b1 & 0xFFFF0000u) | (b0 >> 16);
    unsigned hi1 = (b3 & 0xFFFF0000u) | (b2 >> 16);
    f32x4 r;
    r.x = v.x - bcast_f(b0 & 0xFFFF0000u);
    r.y = v.y - bcast_f(b1 & 0xFFFF0000u);
    r.z = v.z - bcast_f(b2 & 0xFFFF0000u);
    r.w = v.w - bcast_f(b3 & 0xFFFF0000u);
    unsigned c0 = fbits(r.x), c1 = fbits(r.y), c2 = fbits(r.z), c3 = fbits(r.w);
    unsigned lo0 = (c1 & 0xFFFF0000u) | (c0 >> 16);
    unsigned lo1 = (c3 & 0xFFFF0000u) | (c2 >> 16);
    u32x2 hw; hw.x = hi0; hw.y = hi1;
    u32x2 lw; lw.x = lo0; lw.y = lo1;
    st_coh_u32x2((unsigned*)(dst + tid * 64 + u * 4), hw);
    st_coh_u32x2((unsigned*)(dst + 32768 + tid * 64 + u * 4), lw);
  }
}

__global__ void gru_init(float* __restrict__ ws) {
  unsigned* fl = (unsigned*)(ws + OFF_FLAGS);
  st_coh_u32(&fl[threadIdx.x], 0u);  // 1 block x 256 threads
}

__global__ __launch_bounds__(NTHR, 1) void gru_persist(
    const float* __restrict__ x, const float* __restrict__ h0,
    const float* __restrict__ w_ih, const float* __restrict__ w_hh,
    const float* __restrict__ b_ih, const float* __restrict__ b_hh,
    float* __restrict__ out, float* __restrict__ ws) {
  __shared__ float part[24 * 256];    // 24 KB: 24 C-tiles of 16x16 fp32
  __shared__ float h_state[64 * 16];  // 4 KB exact fp32 h for this WG
  __shared__ float bias_sh[96];       // [g][side][j]

  const int tid = threadIdx.x;
  const int lane = tid & 63;
  const int wave = __builtin_amdgcn_readfirstlane(tid >> 6);
  const int wg = blockIdx.x;
  const int layer = wg >> 5;       // 0 or 1
  const int j0 = (wg & 31) << 4;   // 16 hidden cols per WG

  unsigned* flags = (unsigned*)(ws + OFF_FLAGS);
  unsigned short* ring1 = (unsigned short*)(ws + OFF_RING1);
  unsigned short* ring2 = (unsigned short*)(ws + OFF_RING2);

  // ---- prologue A: split x into the out[] slabs (bf16 hi/lo), h0 -> rings
  for (int i = 0; i < 8; ++i) {
    const int t = wg * 8 + i;
    split_slab(x + (size_t)t * 32768, (unsigned short*)(out + (size_t)t * 32768), tid);
  }
  if (wg == 0) split_slab(h0, ring1, tid);          // ring1 slot 0 = h0 L1
  if (wg == 1) split_slab(h0 + 32768, ring2, tid);  // ring2 slot 0 = h0 L2

  // ---- prologue B: biases + h_state into LDS
  if (tid < 96) {
    const int g = tid >> 5, side = (tid >> 4) & 1, j = tid & 15;
    bias_sh[tid] = (side ? b_hh : b_ih)[layer * 1536 + g * 512 + j0 + j];
  }
  {
    const int idx0 = tid * 2;
    const int b0 = idx0 >> 4, jj0 = idx0 & 15;
    h_state[idx0] = h0[((size_t)(layer * 64 + b0)) * 512 + j0 + jj0];
    h_state[idx0 + 1] = h0[((size_t)(layer * 64 + b0)) * 512 + j0 + jj0 + 1];
  }

  // ---- prologue C: stationary B-fragments (weights) in VGPRs
  const int g = wave % 3;       // gate (r,z,n) for compute waves
  const int kh = wave / 3;      // K-half: 0 = input side, 1 = hidden side
  s16x8 bhi[16], blo[16];
  if (wave < 6) {
    const float* Wb = (kh ? w_hh : w_ih) + (size_t)layer * 1536 * 512 +
                      (size_t)(g * 512 + j0 + (lane & 15)) * 512 +
                      ((lane >> 4) * 8);
#pragma unroll
    for (int k = 0; k < 16; ++k) {
      const float* p = Wb + k * 32;
      s16x8 vh, vl;
#pragma unroll
      for (int e = 0; e < 8; ++e) {
        float w = p[e];
        unsigned hb = fbits(w) >> 16;
        float r = w - bcast_f(hb << 16);
        vh[e] = (short)hb;
        vl[e] = (short)(fbits(r) >> 16);
      }
      bhi[k] = vh;
      blo[k] = vl;
    }
  }

  // ---- prologue barrier (flag round 1) ----
  asm volatile("s_waitcnt vmcnt(0)" ::: "memory");
  __syncthreads();
  if (tid == 0) st_coh_u32(&flags[wg], 1u);
  if (wave == 7) {
    const unsigned* fp = flags + (lane & 15) * 4;
    for (;;) {
      u32x4 f; LDC4U(f, fp);
      asm volatile("s_waitcnt vmcnt(0)" ::: "memory");
      int ok = (lane >= 16) ||
               ((f.x >= 1u) && (f.y >= 1u) && (f.z >= 1u) && (f.w >= 1u));
      if (__all(ok)) break;
      __builtin_amdgcn_s_sleep(1);
    }
  }
  __syncthreads();

  const int laneoff = (lane & 15) * 512 + ((lane >> 4) * 8);

  for (int s = 0; s <= GB_T; ++s) {
    const int t = layer ? s - 1 : s;
    const bool active = layer ? (s >= 1) : (s < GB_T);

    if (active && wave < 6) {
      // A slab (bf16 hi at +0, lo at +32768 ushorts), fresh-address cached.
      const unsigned short* slab;
      if (layer == 0)
        slab = kh ? ring1 + (size_t)t * 65536
                  : (const unsigned short*)(out + (size_t)t * 32768);
      else
        slab = kh ? ring2 + (size_t)t * 65536
                  : ring1 + (size_t)(t + 1) * 65536;

      f32x4 acc[4];
#pragma unroll
      for (int m = 0; m < 4; ++m) acc[m] = (f32x4)(0.f);

#pragma unroll
      for (int k = 0; k < 16; ++k) {
#pragma unroll
        for (int m = 0; m < 4; ++m) {
          const int off = m * 8192 + k * 32 + laneoff;
          s16x8 ah = *(const s16x8*)(slab + off);
          s16x8 al = *(const s16x8*)(slab + 32768 + off);
          acc[m] = __builtin_amdgcn_mfma_f32_16x16x32_bf16(ah, bhi[k], acc[m], 0, 0, 0);
          acc[m] = __builtin_amdgcn_mfma_f32_16x16x32_bf16(ah, blo[k], acc[m], 0, 0, 0);
          acc[m] = __builtin_amdgcn_mfma_f32_16x16x32_bf16(al, bhi[k], acc[m], 0, 0, 0);
        }
      }
      // write C tiles: D[row][col], col=lane&15, row=(lane>>4)*4+r
      const int tbase = ((g * 2 + kh) * 4) * 256;
#pragma unroll
      for (int m = 0; m < 4; ++m)
#pragma unroll
        for (int r = 0; r < 4; ++r)
          part[tbase + m * 256 + (((lane >> 4) * 4) + r) * 16 + (lane & 15)] =
              acc[m][r];
    }
    __syncthreads();

    if (active) {
      // epilogue: each thread handles (b, j) and (b, j+1)
      const int b = tid >> 3, jp = (tid & 7) * 2;
      const int m = b >> 4, row = b & 15;
      float hv[2];
#pragma unroll
      for (int p = 0; p < 2; ++p) {
        const int j = jp + p;
        float X[3], H[3];
#pragma unroll
        for (int gg = 0; gg < 3; ++gg) {
          X[gg] = part[((gg * 2 + 0) * 4 + m) * 256 + row * 16 + j] +
                  bias_sh[gg * 32 + j];
          H[gg] = part[((gg * 2 + 1) * 4 + m) * 256 + row * 16 + j] +
                  bias_sh[gg * 32 + 16 + j];
        }
        const float r = 1.f / (1.f + __expf(-(X[0] + H[0])));
        const float z = 1.f / (1.f + __expf(-(X[1] + H[1])));
        const float a = X[2] + r * H[2];
        const float n = 1.f - 2.f / (1.f + __expf(2.f * a));
        const float ho = h_state[b * 16 + j];
        const float hn = (1.f - z) * n + z * ho;
        h_state[b * 16 + j] = hn;
        hv[p] = hn;
      }
      // stores: split-bf16 to ring (slot t+1), fp32 to out for layer 2
      unsigned q0 = fbits(hv[0]), q1 = fbits(hv[1]);
      unsigned hiw = (q1 & 0xFFFF0000u) | (q0 >> 16);
      float r0 = hv[0] - bcast_f(q0 & 0xFFFF0000u);
      float r1 = hv[1] - bcast_f(q1 & 0xFFFF0000u);
      unsigned low = (fbits(r1) & 0xFFFF0000u) | (fbits(r0) >> 16);
      unsigned short* rdst = (layer ? ring2 : ring1) +
                             (size_t)(t + 1) * 65536 + b * 512 + j0 + jp;
      st_coh_u32((unsigned*)rdst, hiw);
      st_coh_u32((unsigned*)(rdst + 32768), low);
      if (layer) {
        u32x2 fo; fo.x = q0; fo.y = q1;
        st_coh_u32x2((unsigned*)(out + (size_t)t * 32768 + b * 512 + j0 + jp), fo);
      }
    }

    // ---- grid barrier ----
    if (s < GB_T) {
      asm volatile("s_waitcnt vmcnt(0)" ::: "memory");
      __syncthreads();
      if (tid == 0) st_coh_u32(&flags[wg], (unsigned)(s + 2));
      if (wave == 7) {
        const unsigned tgt = (unsigned)(s + 2);
        const unsigned* fp = flags + (lane & 15) * 4;
        for (;;) {
          u32x4 f; LDC4U(f, fp);
          asm volatile("s_waitcnt vmcnt(0)" ::: "memory");
          int ok = (lane >= 16) || ((f.x >= tgt) && (f.y >= tgt) &&
                                    (f.z >= tgt) && (f.w >= tgt));
          if (__all(ok)) break;
          __builtin_amdgcn_s_sleep(1);
        }
      }
      __syncthreads();
    }
  }
  asm volatile("s_waitcnt vmcnt(0)" ::: "memory");  // drain final stores
}

extern "C" void kernel_launch(void* const* d_in, const int* in_sizes, int n_in,
                              void* d_out, int out_size, void* d_ws,
                              size_t ws_size, hipStream_t stream) {
  const float* x = (const float*)d_in[0];
  const float* h0 = (const float*)d_in[1];
  const float* w_ih = (const float*)d_in[2];
  const float* w_hh = (const float*)d_in[3];
  const float* b_ih = (const float*)d_in[4];
  const float* b_hh = (const float*)d_in[5];
  float* out = (float*)d_out;
  float* ws = (float*)d_ws;

  gru_init<<<1, 256, 0, stream>>>(ws);

  void* args[] = {(void*)&x,    (void*)&h0,   (void*)&w_ih, (void*)&w_hh,
                  (void*)&b_ih, (void*)&b_hh, (void*)&out,  (void*)&ws};
  (void)hipLaunchCooperativeKernel((const void*)gru_persist, dim3(NWG),
                                   dim3(NTHR), args, 0, stream);
}

// Round 11
// 3450.158 us; speedup vs baseline: 4.8383x; 4.8383x over previous
//
#include <hip/hip_runtime.h>

// ---------------------------------------------------------------------------
// 2-layer GRU, T=512, B=64, I=H=512, fp32 in/out. Persistent cooperative
// kernel, 64 WGs x 512 thr, layers wavefront-pipelined (513 grid-steps).
// Round 11: MFMA + LDS-staged A-feed.
//  - W stationary in VGPRs as bf16 hi+lo (exact to 2^-16); A as bf16-RNE
//    only (2-term product). Per-step A slab = 64 KB per K-half.
//  - A slabs staged into LDS via global_load_lds (VGPR-free, all 16
//    issues/wave in flight -> ONE exposed L3 round trip per step, vs ~64
//    serial trips in r10 where weights ate all VGPRs).
//  - slabs stored tiled: halfword idx = (k>>3)*512 + row*8 + (k&7). DMA fill
//    is linear; MFMA ds_read_b128 is bank-uniform (8/bank, conflict-free).
//  - part[] C-tiles alias the A-buffer after the MFMA phase (extra sync).
//  - h-state + biases in registers. Fresh-address rings, sc0 sc1 stores,
//    entry acquire fence, 64-packed-flag barrier (r5/r10 scheme).
// ---------------------------------------------------------------------------

typedef float f32x4 __attribute__((ext_vector_type(4)));
typedef short s16x8 __attribute__((ext_vector_type(8)));
typedef unsigned u32x2 __attribute__((ext_vector_type(2)));
typedef unsigned u32x4 __attribute__((ext_vector_type(4)));

#define GB_T 512
#define NWG 64
#define NTHR 512
#define SLAB 32768  // ushorts per bf16 slab (64 KB), covers 64 rows x 512 k

// float-word offsets inside ws
#define OFF_FLAGS 0
#define OFF_RING1 1024                          // 513 slabs x 16384 floats
#define OFF_RING2 (OFF_RING1 + 513 * (SLAB / 2))
// ws bytes ~= (1024 + 2*513*16384)*4 ~= 67.2 MB (same footprint as r5)

__device__ __forceinline__ void st_coh_u32(unsigned* p, unsigned v) {
  asm volatile("global_store_dword %0, %1, off sc0 sc1" ::"v"(p), "v"(v)
               : "memory");
}
__device__ __forceinline__ void st_coh_u32x2(unsigned* p, u32x2 v) {
  asm volatile("global_store_dwordx2 %0, %1, off sc0 sc1" ::"v"(p), "v"(v)
               : "memory");
}
__device__ __forceinline__ void st_coh_u32x4(unsigned* p, u32x4 v) {
  asm volatile("global_store_dwordx4 %0, %1, off sc0 sc1" ::"v"(p), "v"(v)
               : "memory");
}
#define LDC4U(dst, addr)                                  \
  asm volatile("global_load_dwordx4 %0, %1, off sc0 sc1" \
               : "=v"(dst)                                \
               : "v"(addr))

// async global->LDS DMA, 16 B per lane; LDS dest = uniform base + lane*16
__device__ __forceinline__ void dma16(const void* gsrc, void* ldst) {
  __builtin_amdgcn_global_load_lds(
      (const __attribute__((address_space(1))) unsigned*)gsrc,
      (__attribute__((address_space(3))) unsigned*)ldst, 16, 0, 0);
}

__device__ __forceinline__ unsigned rne1(float f) {
  unsigned u = __float_as_uint(f);
  return (u + 0x7FFFu + ((u >> 16) & 1u)) >> 16;
}
__device__ __forceinline__ unsigned pack2(float a, float b) {
  return rne1(a) | (rne1(b) << 16);
}

// fp32 row-major [64][512] slab -> tiled bf16-RNE slab (SLAB ushorts)
__device__ __forceinline__ void convert_slab(const float* __restrict__ src,
                                             unsigned short* __restrict__ dst,
                                             int tid) {
  const int row = tid & 63;
  const int kg0 = tid >> 6;  // 0..7
#pragma unroll
  for (int i = 0; i < 8; ++i) {
    const int kg = kg0 + 8 * i;       // 0..63
    const int k0 = kg * 8;
    const float* s = src + row * 512 + k0;
    f32x4 a = *(const f32x4*)s;
    f32x4 b = *(const f32x4*)(s + 4);
    u32x4 o;
    o.x = pack2(a.x, a.y);
    o.y = pack2(a.z, a.w);
    o.z = pack2(b.x, b.y);
    o.w = pack2(b.z, b.w);
    st_coh_u32x4((unsigned*)(dst + kg * 512 + row * 8), o);
  }
}

__global__ void gru_init(float* __restrict__ ws) {
  unsigned* fl = (unsigned*)(ws + OFF_FLAGS);
  st_coh_u32(&fl[threadIdx.x], 0u);  // 1 block x 256 threads
}

__global__ __launch_bounds__(NTHR, 1) void gru_persist(
    const float* __restrict__ x, const float* __restrict__ h0,
    const float* __restrict__ w_ih, const float* __restrict__ w_hh,
    const float* __restrict__ b_ih, const float* __restrict__ b_hh,
    float* __restrict__ out, float* __restrict__ ws) {
  __shared__ unsigned short alds[2][SLAB];  // 128 KB A staging (both halves)
  float* part = (float*)&alds[0][0];        // alias: 24 C-tiles post-MFMA

  const int tid = threadIdx.x;
  const int lane = tid & 63;
  const int wave = __builtin_amdgcn_readfirstlane(tid >> 6);
  const int wg = blockIdx.x;
  const int layer = wg >> 5;      // 0 or 1
  const int j0 = (wg & 31) << 4;  // 16 hidden cols per WG

  unsigned* flags = (unsigned*)(ws + OFF_FLAGS);
  unsigned short* ring1 = (unsigned short*)(ws + OFF_RING1);
  unsigned short* ring2 = (unsigned short*)(ws + OFF_RING2);

  // ---- prologue A: x -> tiled bf16 scratch in out[] slabs; h0 -> rings ----
  for (int i = 0; i < 8; ++i) {
    const int t = wg * 8 + i;
    convert_slab(x + (size_t)t * 32768,
                 (unsigned short*)(out + (size_t)t * 32768), tid);
  }
  if (wg == 0) convert_slab(h0, ring1, tid);
  if (wg == 1) convert_slab(h0 + 32768, ring2, tid);

  // ---- prologue B: stationary weights (bf16 hi+lo) in VGPRs --------------
  const int g = wave % 3;   // gate for compute waves 0..5
  const int kh = wave / 3;  // K-half: 0 = input side, 1 = hidden side
  s16x8 bhi[16], blo[16];
  if (wave < 6) {
    const float* Wb = (kh ? w_hh : w_ih) + (size_t)layer * 1536 * 512 +
                      (size_t)(g * 512 + j0 + (lane & 15)) * 512 +
                      ((lane >> 4) * 8);
#pragma unroll
    for (int k = 0; k < 16; ++k) {
      const float* p = Wb + k * 32;
      s16x8 vh, vl;
#pragma unroll
      for (int e = 0; e < 8; ++e) {
        float w = p[e];
        unsigned hb = __float_as_uint(w) & 0xFFFF0000u;
        float resid = w - __uint_as_float(hb);
        vh[e] = (short)(hb >> 16);
        vl[e] = (short)(__float_as_uint(resid) >> 16);
      }
      bhi[k] = vh;
      blo[k] = vl;
    }
  }

  // ---- prologue C: per-thread epilogue state (h, biases) in registers ----
  const int eb = tid >> 3;          // batch row 0..63
  const int ejp = (tid & 7) * 2;    // col-pair base 0..14
  float hprev0 = h0[((size_t)(layer * 64 + eb)) * 512 + j0 + ejp];
  float hprev1 = h0[((size_t)(layer * 64 + eb)) * 512 + j0 + ejp + 1];
  float bx0[3], bx1[3], bh0[3], bh1[3];
#pragma unroll
  for (int gg = 0; gg < 3; ++gg) {
    bx0[gg] = b_ih[layer * 1536 + gg * 512 + j0 + ejp];
    bx1[gg] = b_ih[layer * 1536 + gg * 512 + j0 + ejp + 1];
    bh0[gg] = b_hh[layer * 1536 + gg * 512 + j0 + ejp];
    bh1[gg] = b_hh[layer * 1536 + gg * 512 + j0 + ejp + 1];
  }

  // Drop stale cache lines (poison / prior replay) before any cached read of
  // mutable slabs.
  __builtin_amdgcn_fence(__ATOMIC_ACQUIRE, "agent");

  // ---- prologue barrier (flag value 1) ----
  asm volatile("s_waitcnt vmcnt(0)" ::: "memory");
  __syncthreads();
  if (tid == 0) st_coh_u32(&flags[wg], 1u);
  if (wave == 7) {
    const unsigned* fp = flags + (lane & 15) * 4;
    for (;;) {
      u32x4 f;
      LDC4U(f, fp);
      asm volatile("s_waitcnt vmcnt(0)" ::: "memory");
      int ok = (lane >= 16) ||
               ((f.x >= 1u) && (f.y >= 1u) && (f.z >= 1u) && (f.w >= 1u));
      if (__all(ok)) break;
      __builtin_amdgcn_s_sleep(1);
    }
  }
  __syncthreads();

  const int l15 = lane & 15, lg = lane >> 4;
  const int em = eb >> 4, erow = eb & 15;

  for (int s = 0; s <= GB_T; ++s) {
    const int t = layer ? s - 1 : s;
    const bool active = layer ? (s >= 1) : (s < GB_T);

    // ---- stage both A halves into LDS via DMA (VGPR-free, deep MLP) ----
    if (active) {
      const char* src0;
      const char* src1;
      if (layer == 0) {
        src0 = (const char*)(out + (size_t)t * 32768);          // x-scratch
        src1 = (const char*)(ring1 + (size_t)t * SLAB);         // h1[t-1]
      } else {
        src0 = (const char*)(ring1 + (size_t)(t + 1) * SLAB);   // h1[t]
        src1 = (const char*)(ring2 + (size_t)t * SLAB);         // h2[t-1]
      }
#pragma unroll
      for (int i = 0; i < 8; ++i) {
        const int r = wave * 8 + i;  // row 0..63, 1 KB each
        dma16(src0 + r * 1024 + lane * 16, (char*)&alds[0][0] + r * 1024);
        dma16(src1 + r * 1024 + lane * 16, (char*)&alds[1][0] + r * 1024);
      }
    }
    asm volatile("s_waitcnt vmcnt(0)" ::: "memory");
    __syncthreads();

    // ---- MFMA phase ----
    f32x4 acc[4];
#pragma unroll
    for (int m = 0; m < 4; ++m) acc[m] = (f32x4)(0.f);
    if (active && wave < 6) {
      const char* base = (const char*)&alds[kh][0] + lg * 1024 + l15 * 16;
#pragma unroll
      for (int k = 0; k < 16; ++k) {
        const s16x8 bh = bhi[k], bl = blo[k];
#pragma unroll
        for (int m = 0; m < 4; ++m) {
          const s16x8 ah = *(const s16x8*)(base + k * 4096 + m * 256);
          acc[m] =
              __builtin_amdgcn_mfma_f32_16x16x32_bf16(ah, bh, acc[m], 0, 0, 0);
          acc[m] =
              __builtin_amdgcn_mfma_f32_16x16x32_bf16(ah, bl, acc[m], 0, 0, 0);
        }
      }
    }
    __syncthreads();  // all ds_reads done; alds dead -> part[] may overwrite

    if (active && wave < 6) {
      const int tbase = ((g * 2 + kh) * 4) * 256;
#pragma unroll
      for (int m = 0; m < 4; ++m)
#pragma unroll
        for (int r2 = 0; r2 < 4; ++r2)
          part[tbase + m * 256 + (lg * 4 + r2) * 16 + l15] = acc[m][r2];
    }
    __syncthreads();

    // ---- epilogue: gates + h update + stores ----
    if (active) {
      float X0[3], H0[3], X1[3], H1[3];
#pragma unroll
      for (int gg = 0; gg < 3; ++gg) {
        X0[gg] = part[((gg * 2 + 0) * 4 + em) * 256 + erow * 16 + ejp] + bx0[gg];
        H0[gg] = part[((gg * 2 + 1) * 4 + em) * 256 + erow * 16 + ejp] + bh0[gg];
        X1[gg] =
            part[((gg * 2 + 0) * 4 + em) * 256 + erow * 16 + ejp + 1] + bx1[gg];
        H1[gg] =
            part[((gg * 2 + 1) * 4 + em) * 256 + erow * 16 + ejp + 1] + bh1[gg];
      }
      const float r0 = 1.f / (1.f + __expf(-(X0[0] + H0[0])));
      const float z0 = 1.f / (1.f + __expf(-(X0[1] + H0[1])));
      const float a0 = X0[2] + r0 * H0[2];
      const float n0 = 1.f - 2.f / (1.f + __expf(2.f * a0));
      const float hn0 = (1.f - z0) * n0 + z0 * hprev0;
      const float r1 = 1.f / (1.f + __expf(-(X1[0] + H1[0])));
      const float z1 = 1.f / (1.f + __expf(-(X1[1] + H1[1])));
      const float a1 = X1[2] + r1 * H1[2];
      const float n1 = 1.f - 2.f / (1.f + __expf(2.f * a1));
      const float hn1 = (1.f - z1) * n1 + z1 * hprev1;
      hprev0 = hn0;
      hprev1 = hn1;
      // tiled bf16 ring store (slot t+1)
      const int j = j0 + ejp;
      unsigned short* rdst = (layer ? ring2 : ring1) + (size_t)(t + 1) * SLAB +
                             (j >> 3) * 512 + eb * 8 + (j & 7);
      st_coh_u32((unsigned*)rdst, pack2(hn0, hn1));
      if (layer) {
        u32x2 fo;
        fo.x = __float_as_uint(hn0);
        fo.y = __float_as_uint(hn1);
        st_coh_u32x2((unsigned*)(out + (size_t)t * 32768 + eb * 512 + j), fo);
      }
    }

    // ---- grid barrier (flag value s+2) ----
    if (s < GB_T) {
      asm volatile("s_waitcnt vmcnt(0)" ::: "memory");
      __syncthreads();
      if (tid == 0) st_coh_u32(&flags[wg], (unsigned)(s + 2));
      if (wave == 7) {
        const unsigned tgt = (unsigned)(s + 2);
        const unsigned* fp = flags + (lane & 15) * 4;
        for (;;) {
          u32x4 f;
          LDC4U(f, fp);
          asm volatile("s_waitcnt vmcnt(0)" ::: "memory");
          int ok = (lane >= 16) || ((f.x >= tgt) && (f.y >= tgt) &&
                                    (f.z >= tgt) && (f.w >= tgt));
          if (__all(ok)) break;
          __builtin_amdgcn_s_sleep(1);
        }
      }
      __syncthreads();
    }
  }
  asm volatile("s_waitcnt vmcnt(0)" ::: "memory");  // drain final stores
}

extern "C" void kernel_launch(void* const* d_in, const int* in_sizes, int n_in,
                              void* d_out, int out_size, void* d_ws,
                              size_t ws_size, hipStream_t stream) {
  const float* x = (const float*)d_in[0];
  const float* h0 = (const float*)d_in[1];
  const float* w_ih = (const float*)d_in[2];
  const float* w_hh = (const float*)d_in[3];
  const float* b_ih = (const float*)d_in[4];
  const float* b_hh = (const float*)d_in[5];
  float* out = (float*)d_out;
  float* ws = (float*)d_ws;

  gru_init<<<1, 256, 0, stream>>>(ws);

  void* args[] = {(void*)&x,    (void*)&h0,   (void*)&w_ih, (void*)&w_hh,
                  (void*)&b_ih, (void*)&b_hh, (void*)&out,  (void*)&ws};
  (void)hipLaunchCooperativeKernel((const void*)gru_persist, dim3(NWG),
                                   dim3(NTHR), args, 0, stream);
}